// Round 11
// baseline (469.594 us; speedup 1.0000x reference)
//
#include <hip/hip_runtime.h>
#include <cstdint>
#include <cstddef>
#include <math.h>

#define B_ 4
#define T_ 1024
#define D_ 512
#define H_ 8
#define E_ 8
#define F_ 1024
#define NTOK (B_*T_)   // 4096
#define HD   (H_*D_)   // 4096
#define PACKF (36*16384)   // f32 per packed causal S slice (36 tiles of 128x128)

typedef float f32x4 __attribute__((ext_vector_type(4)));
typedef short bf16x8 __attribute__((ext_vector_type(8)));
typedef _Float16 f16x8 __attribute__((ext_vector_type(8)));
typedef unsigned short us;

union H16 { _Float16 h; unsigned short u; };

__device__ __forceinline__ us f2b(float f){
  union { float f; unsigned u; } v; v.f = f;
  unsigned r = v.u + 0x7fffu + ((v.u >> 16) & 1u);
  return (us)(r >> 16);
}
__device__ __forceinline__ float b2f(us h){
  union { unsigned u; float f; } v; v.u = ((unsigned)h) << 16; return v.f;
}
__device__ __forceinline__ void splitf(float x, us& hi, us& lo){
  H16 a, b;
  a.h = (_Float16)x;
  b.h = (_Float16)(x - (float)a.h);
  hi = a.u; lo = b.u;
}

// ---------------------------------------------------------------------------
// fp16-split GEMM (3-product Markidis, ~f32). 128x128 tile, BK=32, 4 waves.
// LDS = 4 planes x 8KB = 32KB -> 5 blocks/CU (vs 2 at BK=64): barrier stalls
// of one block overlap other blocks' compute (m114 mechanism).
// Slot swizzle for BK=32 (4 slots/row, row stride 64B): slot ^= (row>>1)&3
// -> banks perfectly balanced (8 words/bank per wave b128 access).
// MODE 1: generic, split hi/lo store.
// MODE 4: generic, RoPE epilogue (interleaved pair cols) + split store.
// MODE 2: attention S. Grid (Z, 8, 8): z in blockIdx.x -> xcd = z%8 = head;
//         rt = 7-by (heavy first), ct = bz, skip ct > rt. Packed causal store.
// MODE 5: attention PV, packed P operand; grid (Z, 8, 4). Per-head fp16
//         partial store, K limited to m0+128, no atomics.
// ---------------------------------------------------------------------------
template<int MODE>
__global__ __launch_bounds__(256, 2) void gemm_ms(
    const us* __restrict__ Ah, const us* __restrict__ Al,
    const us* __restrict__ Bh, const us* __restrict__ Bl,
    float* __restrict__ C, us* __restrict__ Ch, us* __restrict__ Cl,
    int M, int N, int K, int lda, int ldb, int ldc,
    const float2* __restrict__ cspar, int bbase)
{
  int zi, m0, n0;
  if (MODE == 2 || MODE == 5) {
    zi = blockIdx.x;                      // xcd = zi % 8 = head
    int rt = 7 - (int)blockIdx.y;         // heavy rows dispatched first
    int ct = blockIdx.z;
    if (MODE == 2 && ct > rt) return;     // fully-masked causal tiles
    m0 = rt*128; n0 = ct*128;
  } else {
    zi = blockIdx.z;
    m0 = blockIdx.y*128; n0 = blockIdx.x*128;
  }
  const int zb = bbase + (zi >> 3), zh = zi & 7;
  if (MODE == 2) {
    Ah += (size_t)zb*T_*HD + (size_t)zh*D_;
    Al += (size_t)zb*T_*HD + (size_t)zh*D_;
    Bh += (size_t)zb*T_*D_;
    Bl += (size_t)zb*T_*D_;
    C  += (size_t)zi*PACKF;
  } else if (MODE == 5) {
    Bh += (size_t)zh*D_*NTOK + (size_t)zb*T_;
    Bl += (size_t)zh*D_*NTOK + (size_t)zb*T_;
    Ch += (size_t)(zb*8 + zh)*T_*D_;     // per-(b,h) partial slice
  }

  __shared__ char sm[32768];
  char* sAh = sm;
  char* sAl = sm + 8192;
  char* sBh = sm + 16384;
  char* sBl = sm + 24576;
  const int tid = threadIdx.x;
  const int wid = tid >> 6, lane = tid & 63;
  const int wy = wid >> 1, wx = wid & 1;
  const int r16 = lane & 15, g4 = lane >> 4;

  f32x4 acc[4][4];
  #pragma unroll
  for (int i=0;i<4;i++)
    #pragma unroll
    for(int j=0;j<4;j++) acc[i][j] = (f32x4)0.f;

  int nkt = K >> 5;
  if (MODE == 5) nkt = (m0 + 128) >> 5;
  // packed-P tile base (per-z, per-block-row) for MODE 5
  const size_t ztri = (MODE == 5) ? ((size_t)zi*36 + (size_t)(m0>>7)*((m0>>7)+1)/2) : 0;

  for (int kt = 0; kt < nkt; ++kt) {
    #pragma unroll
    for (int r = 0; r < 2; ++r) {
      int linear = r*256 + tid;          // [0,512)
      int row = linear >> 2, ss = linear & 3;
      int sg = ss ^ ((row >> 1) & 3);
      if (MODE == 5) {
        size_t tb = (ztri + (size_t)(kt>>2))*32768;
        int kc = ((kt&3)<<5) | (sg*8);
        __builtin_amdgcn_global_load_lds(
          (const __attribute__((address_space(1))) void*)(Ah + tb + row*256 + kc),
          (__attribute__((address_space(3))) void*)(sAh + linear*16), 16, 0, 0);
        __builtin_amdgcn_global_load_lds(
          (const __attribute__((address_space(1))) void*)(Ah + tb + row*256 + 128 + kc),
          (__attribute__((address_space(3))) void*)(sAl + linear*16), 16, 0, 0);
      } else {
        size_t ga = (size_t)(m0+row)*lda + kt*32 + sg*8;
        __builtin_amdgcn_global_load_lds((const __attribute__((address_space(1))) void*)(Ah + ga),
          (__attribute__((address_space(3))) void*)(sAh + linear*16), 16, 0, 0);
        __builtin_amdgcn_global_load_lds((const __attribute__((address_space(1))) void*)(Al + ga),
          (__attribute__((address_space(3))) void*)(sAl + linear*16), 16, 0, 0);
      }
      size_t gb = (size_t)(n0+row)*ldb + kt*32 + sg*8;
      __builtin_amdgcn_global_load_lds((const __attribute__((address_space(1))) void*)(Bh + gb),
        (__attribute__((address_space(3))) void*)(sBh + linear*16), 16, 0, 0);
      __builtin_amdgcn_global_load_lds((const __attribute__((address_space(1))) void*)(Bl + gb),
        (__attribute__((address_space(3))) void*)(sBl + linear*16), 16, 0, 0);
    }
    __syncthreads();
    {
      f16x8 ah[4], al[4], bh[4], bl[4];
      #pragma unroll
      for (int i=0;i<4;i++){
        int row = wy*64 + i*16 + r16;
        int sl = g4 ^ ((row >> 1) & 3);
        ah[i] = *(const f16x8*)(sAh + row*64 + sl*16);
        al[i] = *(const f16x8*)(sAl + row*64 + sl*16);
      }
      #pragma unroll
      for (int j=0;j<4;j++){
        int row = wx*64 + j*16 + r16;
        int sl = g4 ^ ((row >> 1) & 3);
        bh[j] = *(const f16x8*)(sBh + row*64 + sl*16);
        bl[j] = *(const f16x8*)(sBl + row*64 + sl*16);
      }
      #pragma unroll
      for (int i=0;i<4;i++)
        #pragma unroll
        for (int j=0;j<4;j++) {
          acc[i][j] = __builtin_amdgcn_mfma_f32_16x16x32_f16(ah[i], bh[j], acc[i][j], 0,0,0);
          acc[i][j] = __builtin_amdgcn_mfma_f32_16x16x32_f16(ah[i], bl[j], acc[i][j], 0,0,0);
          acc[i][j] = __builtin_amdgcn_mfma_f32_16x16x32_f16(al[i], bh[j], acc[i][j], 0,0,0);
        }
    }
    __syncthreads();
  }

  const int tidx = (MODE == 2) ? ((m0>>7)*((m0>>7)+1)/2 + (n0>>7)) : 0;
  #pragma unroll
  for (int i=0;i<4;i++) {
    #pragma unroll
    for (int reg=0; reg<4; ++reg) {
      int lm = wy*64 + i*16 + g4*4 + reg;
      int m = m0 + lm;
      int t = m & (T_-1);
      #pragma unroll
      for (int j=0;j<4;j++) {
        int ln = wx*64 + j*16 + r16;
        int n = n0 + ln;
        float v = acc[i][j][reg];
        if (MODE == 2) {
          C[(size_t)tidx*16384 + lm*128 + ln] = v;
        } else if (MODE == 1) {
          us hi, lo; splitf(v, hi, lo);
          Ch[(size_t)m*ldc + n] = hi;
          Cl[(size_t)m*ldc + n] = lo;
        } else if (MODE == 4) {
          float vp = __shfl_xor(v, 1);
          float2 c = cspar[(size_t)t*256 + ((n>>1) & 255)];
          float r = (r16 & 1) ? (v*c.x + vp*c.y) : (v*c.x - vp*c.y);
          us hi, lo; splitf(r, hi, lo);
          Ch[(size_t)m*ldc + n] = hi;
          Cl[(size_t)m*ldc + n] = lo;
        } else {  // MODE 5: plain fp16 partial store
          H16 hx; hx.h = (_Float16)v;
          Ch[(size_t)m*ldc + n] = hx.u;
        }
      }
    }
  }
}

// ---------------------------------------------------------------------------
// Row softmax on packed causal S (z slices of 36 tiles): scale + mask +
// normalize; overwrite each 128-f32 row segment with 128 hi + 128 lo fp16.
// blockIdx.x = z*T + t.
// ---------------------------------------------------------------------------
__global__ void softmax_pk(float* __restrict__ S)
{
  const int row = blockIdx.x;
  const int z = row >> 10, t = row & (T_-1);
  const int ty = t >> 7;
  const int tri = ty*(ty+1)/2;
  const int ncol = (ty+1)*128;
  float* Sz = S + (size_t)z*PACKF;
  const int tid = threadIdx.x;
  const int wid = tid >> 6, lane = tid & 63;
  __shared__ float red[8];
  const float scale = 0.044194173824159216f;  // 1/sqrt(512)
  const int c0 = tid*4;
  const bool act = (c0 < ncol);
  float* seg = Sz + (size_t)(tri + (c0>>7))*16384 + (t & 127)*128;
  float a[4] = {-1e30f,-1e30f,-1e30f,-1e30f};
  if (act) {
    float4 v = *(const float4*)(seg + (c0 & 127));
    a[0] = (c0+0 <= t) ? v.x*scale : -1e30f;
    a[1] = (c0+1 <= t) ? v.y*scale : -1e30f;
    a[2] = (c0+2 <= t) ? v.z*scale : -1e30f;
    a[3] = (c0+3 <= t) ? v.w*scale : -1e30f;
  }
  float mx = fmaxf(fmaxf(a[0],a[1]), fmaxf(a[2],a[3]));
  #pragma unroll
  for (int m=1; m<64; m<<=1) mx = fmaxf(mx, __shfl_xor(mx, m));
  if (lane == 0) red[wid] = mx;
  __syncthreads();
  mx = fmaxf(fmaxf(red[0],red[1]), fmaxf(red[2],red[3]));
  float p[4];
  float ps = 0.f;
  #pragma unroll
  for (int i=0;i<4;i++) { p[i] = expf(a[i] - mx); ps += p[i]; }
  #pragma unroll
  for (int m=1; m<64; m<<=1) ps += __shfl_xor(ps, m);
  __syncthreads();
  if (lane == 0) red[4+wid] = ps;
  __syncthreads();
  float l = red[4]+red[5]+red[6]+red[7];
  if (act) {
    ushort4 hiv, lov;
    us h0,l0,h1,l1,h2,l2,h3,l3;
    splitf(p[0]/l, h0, l0); splitf(p[1]/l, h1, l1);
    splitf(p[2]/l, h2, l2); splitf(p[3]/l, h3, l3);
    hiv.x=h0; hiv.y=h1; hiv.z=h2; hiv.w=h3;
    lov.x=l0; lov.y=l1; lov.z=l2; lov.w=l3;
    us* sp = (us*)seg;
    *(ushort4*)(sp + (c0 & 127))       = hiv;
    *(ushort4*)(sp + 128 + (c0 & 127)) = lov;
  }
}

// ---------------------------------------------------------------------------
// Sparse MoE w13 GEMM: gathered A rows, interleaved w1/w3, fused SiLU.
// ---------------------------------------------------------------------------
__global__ __launch_bounds__(256, 2) void moe_w13(
    const us* __restrict__ xn2b, const us* __restrict__ w13b,
    const int* __restrict__ cnt, const int* __restrict__ tok_idx,
    us* __restrict__ hb)
{
  const int e = blockIdx.z;
  const int ce = cnt[e];
  const int m0 = blockIdx.y*128, n0 = blockIdx.x*128;
  if (m0 >= ce) return;
  __shared__ char sm[32768];
  __shared__ int sidx[128];
  char* smA = sm;
  char* smB = sm + 16384;
  const int tid = threadIdx.x;
  if (tid < 128) sidx[tid] = tok_idx[e*NTOK + m0 + tid] & (NTOK-1);
  __syncthreads();
  const int wid = tid >> 6, lane = tid & 63;
  const int wy = wid >> 1, wx = wid & 1;
  const int r16 = lane & 15, g4 = lane >> 4;
  const us* Bm = w13b + (size_t)e*2*F_*D_;

  f32x4 acc[4][4];
  #pragma unroll
  for (int i=0;i<4;i++)
    #pragma unroll
    for(int j=0;j<4;j++) acc[i][j] = (f32x4)0.f;

  for (int kt = 0; kt < 8; ++kt) {
    #pragma unroll
    for (int r = 0; r < 4; ++r) {
      int linear = r*256 + tid;
      int row = linear >> 3, ss = linear & 7;
      int sg = ss ^ (row & 7);
      int arow = sidx[row];
      __builtin_amdgcn_global_load_lds(
        (const __attribute__((address_space(1))) void*)(xn2b + (size_t)arow*D_ + kt*64 + sg*8),
        (__attribute__((address_space(3))) void*)(smA + linear*16), 16, 0, 0);
      __builtin_amdgcn_global_load_lds(
        (const __attribute__((address_space(1))) void*)(Bm + (size_t)(n0+row)*D_ + kt*64 + sg*8),
        (__attribute__((address_space(3))) void*)(smB + linear*16), 16, 0, 0);
    }
    __syncthreads();
    #pragma unroll
    for (int kk = 0; kk < 2; ++kk) {
      bf16x8 af[4], bfr[4];
      #pragma unroll
      for (int i=0;i<4;i++){
        int row = wy*64 + i*16 + r16;
        int sl = ((kk<<2) | g4) ^ (row & 7);
        af[i] = *(const bf16x8*)(smA + row*128 + sl*16);
      }
      #pragma unroll
      for (int j=0;j<4;j++){
        int row = wx*64 + j*16 + r16;
        int sl = ((kk<<2) | g4) ^ (row & 7);
        bfr[j] = *(const bf16x8*)(smB + row*128 + sl*16);
      }
      #pragma unroll
      for (int i=0;i<4;i++)
        #pragma unroll
        for (int j=0;j<4;j++)
          acc[i][j] = __builtin_amdgcn_mfma_f32_16x16x32_bf16(af[i], bfr[j], acc[i][j], 0,0,0);
    }
    __syncthreads();
  }

  #pragma unroll
  for (int i=0;i<4;i++) {
    #pragma unroll
    for (int reg=0; reg<4; ++reg) {
      int m = m0 + wy*64 + i*16 + g4*4 + reg;
      #pragma unroll
      for (int j=0;j<4;j++) {
        int n = n0 + wx*64 + j*16 + r16;
        float v = acc[i][j][reg];
        float vp = __shfl_xor(v, 1);
        if (!(r16 & 1)) {   // even lane: v = h1, vp = h3
          float hv = v / (1.f + __expf(-v)) * vp;
          hb[((size_t)e*NTOK + m)*F_ + (n>>1)] = f2b(hv);
        }
      }
    }
  }
}

// ---------------------------------------------------------------------------
// Sparse MoE w2 GEMM: scatter-add epilogue out[tok*D+n] += gate*v.
// ---------------------------------------------------------------------------
__global__ __launch_bounds__(256, 2) void moe_w2(
    const us* __restrict__ hb, const us* __restrict__ w2b,
    const int* __restrict__ cnt, const int* __restrict__ tok_idx,
    const float* __restrict__ tok_gate, float* __restrict__ out)
{
  const int e = blockIdx.z;
  const int ce = cnt[e];
  const int m0 = blockIdx.y*128, n0 = blockIdx.x*128;
  if (m0 >= ce) return;
  __shared__ char sm[32768];
  char* smA = sm;
  char* smB = sm + 16384;
  const int tid = threadIdx.x;
  const int wid = tid >> 6, lane = tid & 63;
  const int wy = wid >> 1, wx = wid & 1;
  const int r16 = lane & 15, g4 = lane >> 4;
  const us* Am = hb  + (size_t)e*NTOK*F_;
  const us* Bm = w2b + (size_t)e*D_*F_;

  f32x4 acc[4][4];
  #pragma unroll
  for (int i=0;i<4;i++)
    #pragma unroll
    for(int j=0;j<4;j++) acc[i][j] = (f32x4)0.f;

  for (int kt = 0; kt < 16; ++kt) {
    #pragma unroll
    for (int r = 0; r < 4; ++r) {
      int linear = r*256 + tid;
      int row = linear >> 3, ss = linear & 7;
      int sg = ss ^ (row & 7);
      __builtin_amdgcn_global_load_lds(
        (const __attribute__((address_space(1))) void*)(Am + (size_t)(m0+row)*F_ + kt*64 + sg*8),
        (__attribute__((address_space(3))) void*)(smA + linear*16), 16, 0, 0);
      __builtin_amdgcn_global_load_lds(
        (const __attribute__((address_space(1))) void*)(Bm + (size_t)(n0+row)*F_ + kt*64 + sg*8),
        (__attribute__((address_space(3))) void*)(smB + linear*16), 16, 0, 0);
    }
    __syncthreads();
    #pragma unroll
    for (int kk = 0; kk < 2; ++kk) {
      bf16x8 af[4], bfr[4];
      #pragma unroll
      for (int i=0;i<4;i++){
        int row = wy*64 + i*16 + r16;
        int sl = ((kk<<2) | g4) ^ (row & 7);
        af[i] = *(const bf16x8*)(smA + row*128 + sl*16);
      }
      #pragma unroll
      for (int j=0;j<4;j++){
        int row = wx*64 + j*16 + r16;
        int sl = ((kk<<2) | g4) ^ (row & 7);
        bfr[j] = *(const bf16x8*)(smB + row*128 + sl*16);
      }
      #pragma unroll
      for (int i=0;i<4;i++)
        #pragma unroll
        for (int j=0;j<4;j++)
          acc[i][j] = __builtin_amdgcn_mfma_f32_16x16x32_bf16(af[i], bfr[j], acc[i][j], 0,0,0);
    }
    __syncthreads();
  }

  #pragma unroll
  for (int i=0;i<4;i++) {
    #pragma unroll
    for (int reg=0; reg<4; ++reg) {
      int m = m0 + wy*64 + i*16 + g4*4 + reg;
      if (m < ce) {
        int tok = tok_idx[e*NTOK + m] & (NTOK-1);
        float g = tok_gate[e*NTOK + m];
        #pragma unroll
        for (int j=0;j<4;j++) {
          int n = n0 + wx*64 + j*16 + r16;
          unsafeAtomicAdd(&out[(size_t)tok*D_ + n], g * acc[i][j][reg]);
        }
      }
    }
  }
}

// ---------------------------------------------------------------------------
__global__ void rope_table(const int* __restrict__ pos, float2* __restrict__ cs)
{
  int idx = blockIdx.x*256 + threadIdx.x;   // T*256
  int t = idx >> 8, j = idx & 255;
  float xj = (float)j * (1.0f/256.0f);
  float p32 = (float)pow(10000.0, (double)xj);
  float invf = 1.0f / p32;
  float ang = (float)pos[t] * invf;
  cs[idx] = make_float2(cosf(ang), sinf(ang));
}

// ---------------------------------------------------------------------------
// LN1 -> xn1 fp16 hi/lo planes + roped K planes (interleaved pair order)
// ---------------------------------------------------------------------------
__global__ void ln1_kernel(const float* __restrict__ x, const float* __restrict__ g,
    const float* __restrict__ be, const float2* __restrict__ cs,
    us* __restrict__ xn1h, us* __restrict__ xn1l,
    us* __restrict__ Krh, us* __restrict__ Krl)
{
  const int row = blockIdx.x;           // b*T + t
  const int t = row & (T_-1);
  const int tid = threadIdx.x;
  __shared__ float red[8];
  float v0 = x[(size_t)row*D_ + tid];
  float v1 = x[(size_t)row*D_ + 256 + tid];
  const int wid = tid>>6, lane = tid&63;
  float s = v0 + v1;
  #pragma unroll
  for (int m=1; m<64; m<<=1) s += __shfl_xor(s,m);
  if (lane == 0) red[wid] = s;
  __syncthreads();
  s = red[0]+red[1]+red[2]+red[3];
  float mu = s * (1.f/D_);
  float d0 = v0-mu, d1 = v1-mu;
  float q = d0*d0 + d1*d1;
  #pragma unroll
  for (int m=1; m<64; m<<=1) q += __shfl_xor(q,m);
  __syncthreads();
  if (lane == 0) red[wid] = q;
  __syncthreads();
  q = red[0]+red[1]+red[2]+red[3];
  float var = q * (1.f/D_);
  float rs = rsqrtf(var + 1e-5f);
  float n0 = d0*rs*g[tid]     + be[tid];
  float n1 = d1*rs*g[tid+256] + be[tid+256];
  splitf(n0, xn1h[(size_t)row*D_ + tid],       xn1l[(size_t)row*D_ + tid]);
  splitf(n1, xn1h[(size_t)row*D_ + 256 + tid], xn1l[(size_t)row*D_ + 256 + tid]);
  float2 c = cs[(size_t)t*256 + tid];
  float k0 = n0*c.x - n1*c.y;
  float k1 = n1*c.x + n0*c.y;
  us k0h,k0l,k1h,k1l;
  splitf(k0, k0h, k0l);
  splitf(k1, k1h, k1l);
  size_t kb = (size_t)row*D_ + 2*tid;
  *(unsigned*)(Krh + kb) = (unsigned)k0h | ((unsigned)k1h << 16);
  *(unsigned*)(Krl + kb) = (unsigned)k0l | ((unsigned)k1l << 16);
}

// ---------------------------------------------------------------------------
// Transpose-split both M (with RoPE pair permutation) and V in one launch.
// ---------------------------------------------------------------------------
__global__ void transpose_split2(const float* __restrict__ Mp, const float* __restrict__ Vp,
    us* __restrict__ Mth, us* __restrict__ Mtl,
    us* __restrict__ Vth, us* __restrict__ Vtl)
{
  const int zz = blockIdx.z;
  const float* in = zz ? Vp : Mp;
  us* outh = zz ? Vth : Mth;
  us* outl = zz ? Vtl : Mtl;
  const int R = D_, C = HD;
  __shared__ float tile[32][33];
  const int c0 = blockIdx.x*32, r0 = blockIdx.y*32;
  const int tc = threadIdx.x & 31, tr = threadIdx.x >> 5;  // tr in 0..7
  #pragma unroll
  for (int i=0;i<4;i++)
    tile[tr + 8*i][tc] = in[(size_t)(r0 + tr + 8*i)*C + c0 + tc];
  __syncthreads();
  #pragma unroll
  for (int i=0;i<4;i++) {
    float v = tile[tc][tr + 8*i];
    int j0 = c0 + tr + 8*i;
    int n = j0;
    if (!zz) {
      int jh = j0 & 511;
      n = (j0 & ~511) | ((jh & 255) << 1) | (jh >> 8);
    }
    size_t o = (size_t)n*R + r0 + tc;
    splitf(v, outh[o], outl[o]);
  }
}

// ---------------------------------------------------------------------------
// One-shot MoE weight cast: w1 -> w13b rows 2f, w3 -> rows 2f+1, w2 -> w2b.
// ---------------------------------------------------------------------------
__global__ void cast_moe(const float* __restrict__ w1, const float* __restrict__ w3,
    const float* __restrict__ w2, us* __restrict__ w13b, us* __restrict__ w2b)
{
  const int n1 = E_*F_*D_/4;
  int i = blockIdx.x*256 + threadIdx.x;   // 3*n1 total
  const float* src; int kind;
  int ii = i;
  if (i < n1)            { src = w1; kind = 0; }
  else if (i < 2*n1)     { src = w3; kind = 1; ii = i - n1; }
  else                   { src = w2; kind = 2; ii = i - 2*n1; }
  float4 v = ((const float4*)src)[ii];
  union { us u[4]; uint2 v2; } r;
  r.u[0]=f2b(v.x); r.u[1]=f2b(v.y); r.u[2]=f2b(v.z); r.u[3]=f2b(v.w);
  if (kind == 2) {
    ((uint2*)w2b)[ii] = r.v2;
  } else {
    int e = ii / (F_*D_/4);
    int rem = ii - e*(F_*D_/4);
    int f = rem / (D_/4);
    int d4 = rem - f*(D_/4);
    size_t ob = (size_t)e*(2*F_*D_/4) + (size_t)(2*f+kind)*(D_/4) + d4;
    ((uint2*)w13b)[ob] = r.v2;
  }
}

// ---------------------------------------------------------------------------
// x1 = x + sum_h Opart[h]; out = x1; xn2b = bf16(LN2(x1)); fused router logits
// ---------------------------------------------------------------------------
__global__ void resid_ln2_kernel(const float* __restrict__ x, const us* __restrict__ Opart,
    const float* __restrict__ g, const float* __restrict__ be,
    const float* __restrict__ rw,
    float* __restrict__ out, us* __restrict__ xn2b, float* __restrict__ logits)
{
  const int row = blockIdx.x;
  const int b = row >> 10, t = row & (T_-1);
  const int tid = threadIdx.x;
  __shared__ float red[8];
  __shared__ float red2[4][8];
  float a0 = x[(size_t)row*D_ + tid];
  float a1 = x[(size_t)row*D_ + 256 + tid];
  #pragma unroll
  for (int h=0; h<H_; ++h) {
    const us* op = Opart + ((size_t)(b*8 + h)*T_ + t)*D_;
    H16 u0; u0.u = op[tid];       a0 += (float)u0.h;
    H16 u1; u1.u = op[256 + tid]; a1 += (float)u1.h;
  }
  out[(size_t)row*D_ + tid] = a0;
  out[(size_t)row*D_ + 256 + tid] = a1;
  const int wid = tid>>6, lane = tid&63;
  float s = a0 + a1;
  #pragma unroll
  for (int m=1; m<64; m<<=1) s += __shfl_xor(s,m);
  if (lane == 0) red[wid] = s;
  __syncthreads();
  s = red[0]+red[1]+red[2]+red[3];
  float mu = s * (1.f/D_);
  float d0 = a0-mu, d1 = a1-mu;
  float q = d0*d0 + d1*d1;
  #pragma unroll
  for (int m=1; m<64; m<<=1) q += __shfl_xor(q,m);
  __syncthreads();
  if (lane == 0) red[wid] = q;
  __syncthreads();
  q = red[0]+red[1]+red[2]+red[3];
  float var = q * (1.f/D_);
  float rs = rsqrtf(var + 1e-5f);
  float n0 = d0*rs*g[tid]     + be[tid];
  float n1 = d1*rs*g[tid+256] + be[tid+256];
  xn2b[(size_t)row*D_ + tid]       = f2b(n0);
  xn2b[(size_t)row*D_ + 256 + tid] = f2b(n1);
  float pl[8];
  #pragma unroll
  for (int e=0;e<E_;e++)
    pl[e] = n0*rw[e*D_ + tid] + n1*rw[e*D_ + 256 + tid];
  #pragma unroll
  for (int m=1; m<64; m<<=1)
    #pragma unroll
    for (int e=0;e<E_;e++) pl[e] += __shfl_xor(pl[e], m);
  if (lane == 0)
    #pragma unroll
    for (int e=0;e<E_;e++) red2[wid][e] = pl[e];
  __syncthreads();
  if (tid < 8)
    logits[(size_t)row*8 + tid] = red2[0][tid]+red2[1][tid]+red2[2][tid]+red2[3][tid];
}

// ---------------------------------------------------------------------------
// Router compaction: single block, deterministic slot assignment.
// ---------------------------------------------------------------------------
__global__ __launch_bounds__(1024) void router_compact(
    const float* __restrict__ logits, int* __restrict__ cnt,
    int* __restrict__ tok_idx, float* __restrict__ tok_gate)
{
  const int tid = threadIdx.x;
  __shared__ int sc[1024][8];
  int e1v[4], e2v[4];
  float g1v[4], g2v[4];
  int lc[8] = {0,0,0,0,0,0,0,0};
  #pragma unroll
  for (int i=0;i<4;i++) {
    int tok = tid*4 + i;
    float lg[8];
    float4 a = *(const float4*)(logits + (size_t)tok*8);
    float4 b = *(const float4*)(logits + (size_t)tok*8 + 4);
    lg[0]=a.x; lg[1]=a.y; lg[2]=a.z; lg[3]=a.w;
    lg[4]=b.x; lg[5]=b.y; lg[6]=b.z; lg[7]=b.w;
    int i1 = 0;
    #pragma unroll
    for (int e=1;e<E_;e++) if (lg[e] > lg[i1]) i1 = e;
    int i2 = (i1==0) ? 1 : 0;
    #pragma unroll
    for (int e=0;e<E_;e++) if (e != i1 && lg[e] > lg[i2]) i2 = e;
    float p2 = expf(lg[i2] - lg[i1]);
    float den = 1.f + p2;
    e1v[i] = i1; g1v[i] = 1.f/den;
    e2v[i] = i2; g2v[i] = p2/den;
    lc[i1]++; lc[i2]++;
  }
  #pragma unroll
  for (int e=0;e<E_;e++) sc[tid][e] = lc[e];
  __syncthreads();
  for (int off=1; off<1024; off<<=1) {
    int tmp[8];
    if (tid >= off) {
      #pragma unroll
      for (int e=0;e<E_;e++) tmp[e] = sc[tid-off][e];
    }
    __syncthreads();
    if (tid >= off) {
      #pragma unroll
      for (int e=0;e<E_;e++) sc[tid][e] += tmp[e];
    }
    __syncthreads();
  }
  int run[8];
  #pragma unroll
  for (int e=0;e<E_;e++) run[e] = sc[tid][e] - lc[e];   // exclusive prefix
  if (tid == 0) {
    #pragma unroll
    for (int e=0;e<E_;e++) cnt[e] = sc[1023][e];
  }
  #pragma unroll
  for (int i=0;i<4;i++) {
    int tok = tid*4 + i;
    int s1 = run[e1v[i]]++;
    tok_idx[e1v[i]*NTOK + s1]  = tok;
    tok_gate[e1v[i]*NTOK + s1] = g1v[i];
    int s2 = run[e2v[i]]++;
    tok_idx[e2v[i]*NTOK + s2]  = tok;
    tok_gate[e2v[i]*NTOK + s2] = g2v[i];
  }
}

// ---------------------------------------------------------------------------
extern "C" void kernel_launch(void* const* d_in, const int* in_sizes, int n_in,
                              void* d_out, int out_size, void* d_ws, size_t ws_size,
                              hipStream_t stream)
{
  const float* x    = (const float*)d_in[0];
  const int*   pos  = (const int*)d_in[1];
  const float* ln1g = (const float*)d_in[2];
  const float* ln1b = (const float*)d_in[3];
  const float* M    = (const float*)d_in[4];
  const float* V    = (const float*)d_in[5];
  const float* ln2g = (const float*)d_in[6];
  const float* ln2b = (const float*)d_in[7];
  const float* rw   = (const float*)d_in[8];
  const float* w1   = (const float*)d_in[9];
  const float* w2   = (const float*)d_in[10];
  const float* w3   = (const float*)d_in[11];
  float* out = (float*)d_out;

  char* ws = (char*)d_ws;
  const size_t MB = (size_t)1 << 20;
  const bool merged = ws_size >= (size_t)229*MB;

  // --- persistent across attention phase ---
  float2* cs  = (float2*)(ws + 0);            // 2MB
  us* Krh  = (us*)(ws + 2*MB);                // 4MB (interleaved pair order)
  us* Krl  = (us*)(ws + 6*MB);                // 4MB
  us* valTh   = (us*)(ws + 10*MB);            // 32MB (10..42)
  us* valTl   = (us*)(ws + 42*MB);            // 32MB (42..74)
  us* Qhp     = (us*)(ws + 74*MB);            // 32MB (74..106), dead after S-GEMM
  us* Qlp     = (us*)(ws + 106*MB);           // 32MB (106..138), dead after S-GEMM
  float* S    = (float*)(ws + 138*MB);        // packed: 75.5MB (merged) / 18.9MB/b (fallback)
  // projection-phase temporaries overlay the S region (dead before S written)
  us* xn1h = (us*)(ws + 138*MB);              // 4MB
  us* xn1l = (us*)(ws + 142*MB);              // 4MB
  us* Mth  = (us*)(ws + 146*MB);              // 8MB
  us* Mtl  = (us*)(ws + 154*MB);              // 8MB
  us* Vth  = (us*)(ws + 162*MB);              // 8MB
  us* Vtl  = (us*)(ws + 170*MB);              // 8MB (ends 178)
  // Opart (B*H per-head fp16 partials, 32MB):
  //   merged: over dead Q planes at 74MB; fallback: after fallback S at 157MB.
  us* Opart = merged ? (us*)(ws + 74*MB) : (us*)(ws + 157*MB);
  size_t tail = merged ? 214*MB : 190*MB;
  float* logits = (float*)(ws + tail);                    // 128KB
  us*    xn2b   = (us*)   (ws + tail + 1*MB);             // 4MB
  int*   cnt      = (int*)  (ws + tail + 5*MB);           // 4KB
  int*   tok_idx  = (int*)  (ws + tail + 5*MB + 4096);    // 128KB
  float* tok_gate = (float*)(ws + tail + 5*MB + 4096 + 128*1024); // 128KB
  // MoE temporaries overlay attention-dead regions
  us* w13b = (us*)(ws + 10*MB);               // 16MB (over valT, dead post-PV)
  us* w2b  = (us*)(ws + 26*MB);               // 8MB
  us* hb   = (us*)(ws + 74*MB);               // 64MB (over Q/Opart, dead post-resid)

  rope_table<<<T_, 256, 0, stream>>>(pos, cs);
  ln1_kernel<<<NTOK, 256, 0, stream>>>(x, ln1g, ln1b, cs, xn1h, xn1l, Krh, Krl);
  transpose_split2<<<dim3(HD/32, D_/32, 2), 256, 0, stream>>>(M, V, Mth, Mtl, Vth, Vtl);

  // Q = rope(xn1 @ M) fused epilogue -> Qhp/Qlp (interleaved pair order)
  gemm_ms<4><<<dim3(HD/128, NTOK/128, 1), 256, 0, stream>>>(
      xn1h, xn1l, Mth, Mtl, nullptr, Qhp, Qlp,
      NTOK, HD, D_, D_, D_, HD, cs, 0);
  // valT[h,d,b,t] = V^T @ xn1^T, split store
  gemm_ms<1><<<dim3(NTOK/128, HD/128, 1), 256, 0, stream>>>(
      Vth, Vtl, xn1h, xn1l, nullptr, valTh, valTl,
      HD, NTOK, D_, D_, D_, NTOK, nullptr, 0);

  // --- attention: packed causal S -> softmax -> PV ---
  // z-major grids: xcd = z%8 = head; heavy row-tiles dispatched first.
  if (merged) {
    gemm_ms<2><<<dim3(B_*H_, 8, 8), 256, 0, stream>>>(
        Qhp, Qlp, Krh, Krl, S, nullptr, nullptr,
        T_, T_, D_, HD, D_, 128, nullptr, 0);
    softmax_pk<<<B_*H_*T_, 256, 0, stream>>>(S);
    gemm_ms<5><<<dim3(B_*H_, 8, 4), 256, 0, stream>>>(
        (const us*)S, nullptr, valTh, valTl, nullptr, Opart, nullptr,
        T_, D_, T_, 0, NTOK, D_, nullptr, 0);
  } else {
    for (int b = 0; b < B_; ++b) {
      gemm_ms<2><<<dim3(H_, 8, 8), 256, 0, stream>>>(
          Qhp, Qlp, Krh, Krl, S, nullptr, nullptr,
          T_, T_, D_, HD, D_, 128, nullptr, b);
      softmax_pk<<<H_*T_, 256, 0, stream>>>(S);
      gemm_ms<5><<<dim3(H_, 8, 4), 256, 0, stream>>>(
          (const us*)S, nullptr, valTh, valTl, nullptr, Opart, nullptr,
          T_, D_, T_, 0, NTOK, D_, nullptr, b);
    }
  }

  resid_ln2_kernel<<<NTOK, 256, 0, stream>>>(x, Opart, ln2g, ln2b, rw, out, xn2b, logits);
  router_compact<<<1, 1024, 0, stream>>>(logits, cnt, tok_idx, tok_gate);

  cast_moe<<<3*(E_*F_*D_/4)/256, 256, 0, stream>>>(w1, w3, w2, w13b, w2b);

  moe_w13<<<dim3(2*F_/128, NTOK/128, E_), 256, 0, stream>>>(
      xn2b, w13b, cnt, tok_idx, hb);
  moe_w2<<<dim3(D_/128, NTOK/128, E_), 256, 0, stream>>>(
      hb, w2b, cnt, tok_idx, tok_gate, out);
}

// Round 12
// 410.637 us; speedup vs baseline: 1.1436x; 1.1436x over previous
//
#include <hip/hip_runtime.h>
#include <cstdint>
#include <cstddef>
#include <math.h>

#define B_ 4
#define T_ 1024
#define D_ 512
#define H_ 8
#define E_ 8
#define F_ 1024
#define NTOK (B_*T_)   // 4096
#define HD   (H_*D_)   // 4096
#define PACKF (36*16384)   // f32 per packed causal S slice (36 tiles of 128x128)

typedef float f32x4 __attribute__((ext_vector_type(4)));
typedef short bf16x8 __attribute__((ext_vector_type(8)));
typedef _Float16 f16x8 __attribute__((ext_vector_type(8)));
typedef unsigned short us;

union H16 { _Float16 h; unsigned short u; };

__device__ __forceinline__ us f2b(float f){
  union { float f; unsigned u; } v; v.f = f;
  unsigned r = v.u + 0x7fffu + ((v.u >> 16) & 1u);
  return (us)(r >> 16);
}
__device__ __forceinline__ float b2f(us h){
  union { unsigned u; float f; } v; v.u = ((unsigned)h) << 16; return v.f;
}
__device__ __forceinline__ void splitf(float x, us& hi, us& lo){
  H16 a, b;
  a.h = (_Float16)x;
  b.h = (_Float16)(x - (float)a.h);
  hi = a.u; lo = b.u;
}

// ---------------------------------------------------------------------------
// fp16-split GEMM (3-product Markidis, ~f32). 128x128 tile, BK=64, 4 waves.
// NOTE (R11 post-mortem): BK=32 variant regressed (470 vs 413 us) — per-stage
// barrier drain is fixed-cost; halving MFMA/stage doubled the stall fraction.
// Keep BK=64 / 2 blocks/CU.
// MODE 1: generic, split hi/lo store.
// MODE 4: generic, RoPE epilogue (interleaved pair cols) + split store.
// MODE 2: attention S. Grid (Z, 8, 8): z in blockIdx.x -> xcd = z%8 = head;
//         rt = 7-by (heavy first), ct = bz, skip ct > rt. Packed causal store.
// MODE 5: attention PV, packed P operand; grid (Z, 8, 4). Per-head fp16
//         partial store, K limited to m0+128, no atomics.
// ---------------------------------------------------------------------------
template<int MODE>
__global__ __launch_bounds__(256, 2) void gemm_ms(
    const us* __restrict__ Ah, const us* __restrict__ Al,
    const us* __restrict__ Bh, const us* __restrict__ Bl,
    float* __restrict__ C, us* __restrict__ Ch, us* __restrict__ Cl,
    int M, int N, int K, int lda, int ldb, int ldc,
    const float2* __restrict__ cspar, int bbase)
{
  int zi, m0, n0;
  if (MODE == 2 || MODE == 5) {
    zi = blockIdx.x;                      // xcd = zi % 8 = head
    int rt = 7 - (int)blockIdx.y;         // heavy rows dispatched first
    int ct = blockIdx.z;
    if (MODE == 2 && ct > rt) return;     // fully-masked causal tiles
    m0 = rt*128; n0 = ct*128;
  } else {
    zi = blockIdx.z;
    m0 = blockIdx.y*128; n0 = blockIdx.x*128;
  }
  const int zb = bbase + (zi >> 3), zh = zi & 7;
  if (MODE == 2) {
    Ah += (size_t)zb*T_*HD + (size_t)zh*D_;
    Al += (size_t)zb*T_*HD + (size_t)zh*D_;
    Bh += (size_t)zb*T_*D_;
    Bl += (size_t)zb*T_*D_;
    C  += (size_t)zi*PACKF;
  } else if (MODE == 5) {
    Bh += (size_t)zh*D_*NTOK + (size_t)zb*T_;
    Bl += (size_t)zh*D_*NTOK + (size_t)zb*T_;
    Ch += (size_t)(zb*8 + zh)*T_*D_;     // per-(b,h) partial slice
  }

  __shared__ char sm[65536];
  char* sAh = sm;
  char* sAl = sm + 16384;
  char* sBh = sm + 32768;
  char* sBl = sm + 49152;
  const int tid = threadIdx.x;
  const int wid = tid >> 6, lane = tid & 63;
  const int wy = wid >> 1, wx = wid & 1;
  const int r16 = lane & 15, g4 = lane >> 4;

  f32x4 acc[4][4];
  #pragma unroll
  for (int i=0;i<4;i++)
    #pragma unroll
    for(int j=0;j<4;j++) acc[i][j] = (f32x4)0.f;

  int nkt = K >> 6;
  if (MODE == 5) nkt = (m0 + 128) >> 6;
  // packed-P tile base (per-z, per-block-row) for MODE 5
  const size_t ztri = (MODE == 5) ? ((size_t)zi*36 + (size_t)(m0>>7)*((m0>>7)+1)/2) : 0;

  for (int kt = 0; kt < nkt; ++kt) {
    #pragma unroll
    for (int r = 0; r < 4; ++r) {
      int linear = r*256 + tid;
      int row = linear >> 3, ss = linear & 7;
      int sg = ss ^ (row & 7);
      if (MODE == 5) {
        size_t tb = (ztri + (kt>>1))*32768;
        int kc = ((kt&1)<<6) | (sg*8);
        __builtin_amdgcn_global_load_lds(
          (const __attribute__((address_space(1))) void*)(Ah + tb + row*256 + kc),
          (__attribute__((address_space(3))) void*)(sAh + linear*16), 16, 0, 0);
        __builtin_amdgcn_global_load_lds(
          (const __attribute__((address_space(1))) void*)(Ah + tb + row*256 + 128 + kc),
          (__attribute__((address_space(3))) void*)(sAl + linear*16), 16, 0, 0);
      } else {
        size_t ga = (size_t)(m0+row)*lda + kt*64 + sg*8;
        __builtin_amdgcn_global_load_lds((const __attribute__((address_space(1))) void*)(Ah + ga),
          (__attribute__((address_space(3))) void*)(sAh + linear*16), 16, 0, 0);
        __builtin_amdgcn_global_load_lds((const __attribute__((address_space(1))) void*)(Al + ga),
          (__attribute__((address_space(3))) void*)(sAl + linear*16), 16, 0, 0);
      }
      size_t gb = (size_t)(n0+row)*ldb + kt*64 + sg*8;
      __builtin_amdgcn_global_load_lds((const __attribute__((address_space(1))) void*)(Bh + gb),
        (__attribute__((address_space(3))) void*)(sBh + linear*16), 16, 0, 0);
      __builtin_amdgcn_global_load_lds((const __attribute__((address_space(1))) void*)(Bl + gb),
        (__attribute__((address_space(3))) void*)(sBl + linear*16), 16, 0, 0);
    }
    __syncthreads();
    #pragma unroll
    for (int kk = 0; kk < 2; ++kk) {
      f16x8 ah[4], al[4], bh[4], bl[4];
      #pragma unroll
      for (int i=0;i<4;i++){
        int row = wy*64 + i*16 + r16;
        int sl = ((kk<<2) | g4) ^ (row & 7);
        ah[i] = *(const f16x8*)(sAh + row*128 + sl*16);
        al[i] = *(const f16x8*)(sAl + row*128 + sl*16);
      }
      #pragma unroll
      for (int j=0;j<4;j++){
        int row = wx*64 + j*16 + r16;
        int sl = ((kk<<2) | g4) ^ (row & 7);
        bh[j] = *(const f16x8*)(sBh + row*128 + sl*16);
        bl[j] = *(const f16x8*)(sBl + row*128 + sl*16);
      }
      #pragma unroll
      for (int i=0;i<4;i++)
        #pragma unroll
        for (int j=0;j<4;j++) {
          acc[i][j] = __builtin_amdgcn_mfma_f32_16x16x32_f16(ah[i], bh[j], acc[i][j], 0,0,0);
          acc[i][j] = __builtin_amdgcn_mfma_f32_16x16x32_f16(ah[i], bl[j], acc[i][j], 0,0,0);
          acc[i][j] = __builtin_amdgcn_mfma_f32_16x16x32_f16(al[i], bh[j], acc[i][j], 0,0,0);
        }
    }
    __syncthreads();
  }

  const int tidx = (MODE == 2) ? ((m0>>7)*((m0>>7)+1)/2 + (n0>>7)) : 0;
  #pragma unroll
  for (int i=0;i<4;i++) {
    #pragma unroll
    for (int reg=0; reg<4; ++reg) {
      int lm = wy*64 + i*16 + g4*4 + reg;
      int m = m0 + lm;
      int t = m & (T_-1);
      #pragma unroll
      for (int j=0;j<4;j++) {
        int ln = wx*64 + j*16 + r16;
        int n = n0 + ln;
        float v = acc[i][j][reg];
        if (MODE == 2) {
          C[(size_t)tidx*16384 + lm*128 + ln] = v;
        } else if (MODE == 1) {
          us hi, lo; splitf(v, hi, lo);
          Ch[(size_t)m*ldc + n] = hi;
          Cl[(size_t)m*ldc + n] = lo;
        } else if (MODE == 4) {
          float vp = __shfl_xor(v, 1);
          float2 c = cspar[(size_t)t*256 + ((n>>1) & 255)];
          float r = (r16 & 1) ? (v*c.x + vp*c.y) : (v*c.x - vp*c.y);
          us hi, lo; splitf(r, hi, lo);
          Ch[(size_t)m*ldc + n] = hi;
          Cl[(size_t)m*ldc + n] = lo;
        } else {  // MODE 5: plain fp16 partial store
          H16 hx; hx.h = (_Float16)v;
          Ch[(size_t)m*ldc + n] = hx.u;
        }
      }
    }
  }
}

// ---------------------------------------------------------------------------
// Row softmax on packed causal S (z slices of 36 tiles): scale + mask +
// normalize; overwrite each 128-f32 row segment with 128 hi + 128 lo fp16.
// blockIdx.x = z*T + t.
// ---------------------------------------------------------------------------
__global__ void softmax_pk(float* __restrict__ S)
{
  const int row = blockIdx.x;
  const int z = row >> 10, t = row & (T_-1);
  const int ty = t >> 7;
  const int tri = ty*(ty+1)/2;
  const int ncol = (ty+1)*128;
  float* Sz = S + (size_t)z*PACKF;
  const int tid = threadIdx.x;
  const int wid = tid >> 6, lane = tid & 63;
  __shared__ float red[8];
  const float scale = 0.044194173824159216f;  // 1/sqrt(512)
  const int c0 = tid*4;
  const bool act = (c0 < ncol);
  float* seg = Sz + (size_t)(tri + (c0>>7))*16384 + (t & 127)*128;
  float a[4] = {-1e30f,-1e30f,-1e30f,-1e30f};
  if (act) {
    float4 v = *(const float4*)(seg + (c0 & 127));
    a[0] = (c0+0 <= t) ? v.x*scale : -1e30f;
    a[1] = (c0+1 <= t) ? v.y*scale : -1e30f;
    a[2] = (c0+2 <= t) ? v.z*scale : -1e30f;
    a[3] = (c0+3 <= t) ? v.w*scale : -1e30f;
  }
  float mx = fmaxf(fmaxf(a[0],a[1]), fmaxf(a[2],a[3]));
  #pragma unroll
  for (int m=1; m<64; m<<=1) mx = fmaxf(mx, __shfl_xor(mx, m));
  if (lane == 0) red[wid] = mx;
  __syncthreads();
  mx = fmaxf(fmaxf(red[0],red[1]), fmaxf(red[2],red[3]));
  float p[4];
  float ps = 0.f;
  #pragma unroll
  for (int i=0;i<4;i++) { p[i] = expf(a[i] - mx); ps += p[i]; }
  #pragma unroll
  for (int m=1; m<64; m<<=1) ps += __shfl_xor(ps, m);
  __syncthreads();
  if (lane == 0) red[4+wid] = ps;
  __syncthreads();
  float l = red[4]+red[5]+red[6]+red[7];
  if (act) {
    ushort4 hiv, lov;
    us h0,l0,h1,l1,h2,l2,h3,l3;
    splitf(p[0]/l, h0, l0); splitf(p[1]/l, h1, l1);
    splitf(p[2]/l, h2, l2); splitf(p[3]/l, h3, l3);
    hiv.x=h0; hiv.y=h1; hiv.z=h2; hiv.w=h3;
    lov.x=l0; lov.y=l1; lov.z=l2; lov.w=l3;
    us* sp = (us*)seg;
    *(ushort4*)(sp + (c0 & 127))       = hiv;
    *(ushort4*)(sp + 128 + (c0 & 127)) = lov;
  }
}

// ---------------------------------------------------------------------------
// Sparse MoE w13 GEMM: gathered A rows, interleaved w1/w3, fused SiLU.
// ---------------------------------------------------------------------------
__global__ __launch_bounds__(256, 2) void moe_w13(
    const us* __restrict__ xn2b, const us* __restrict__ w13b,
    const int* __restrict__ cnt, const int* __restrict__ tok_idx,
    us* __restrict__ hb)
{
  const int e = blockIdx.z;
  const int ce = cnt[e];
  const int m0 = blockIdx.y*128, n0 = blockIdx.x*128;
  if (m0 >= ce) return;
  __shared__ char sm[32768];
  __shared__ int sidx[128];
  char* smA = sm;
  char* smB = sm + 16384;
  const int tid = threadIdx.x;
  if (tid < 128) sidx[tid] = tok_idx[e*NTOK + m0 + tid] & (NTOK-1);
  __syncthreads();
  const int wid = tid >> 6, lane = tid & 63;
  const int wy = wid >> 1, wx = wid & 1;
  const int r16 = lane & 15, g4 = lane >> 4;
  const us* Bm = w13b + (size_t)e*2*F_*D_;

  f32x4 acc[4][4];
  #pragma unroll
  for (int i=0;i<4;i++)
    #pragma unroll
    for(int j=0;j<4;j++) acc[i][j] = (f32x4)0.f;

  for (int kt = 0; kt < 8; ++kt) {
    #pragma unroll
    for (int r = 0; r < 4; ++r) {
      int linear = r*256 + tid;
      int row = linear >> 3, ss = linear & 7;
      int sg = ss ^ (row & 7);
      int arow = sidx[row];
      __builtin_amdgcn_global_load_lds(
        (const __attribute__((address_space(1))) void*)(xn2b + (size_t)arow*D_ + kt*64 + sg*8),
        (__attribute__((address_space(3))) void*)(smA + linear*16), 16, 0, 0);
      __builtin_amdgcn_global_load_lds(
        (const __attribute__((address_space(1))) void*)(Bm + (size_t)(n0+row)*D_ + kt*64 + sg*8),
        (__attribute__((address_space(3))) void*)(smB + linear*16), 16, 0, 0);
    }
    __syncthreads();
    #pragma unroll
    for (int kk = 0; kk < 2; ++kk) {
      bf16x8 af[4], bfr[4];
      #pragma unroll
      for (int i=0;i<4;i++){
        int row = wy*64 + i*16 + r16;
        int sl = ((kk<<2) | g4) ^ (row & 7);
        af[i] = *(const bf16x8*)(smA + row*128 + sl*16);
      }
      #pragma unroll
      for (int j=0;j<4;j++){
        int row = wx*64 + j*16 + r16;
        int sl = ((kk<<2) | g4) ^ (row & 7);
        bfr[j] = *(const bf16x8*)(smB + row*128 + sl*16);
      }
      #pragma unroll
      for (int i=0;i<4;i++)
        #pragma unroll
        for (int j=0;j<4;j++)
          acc[i][j] = __builtin_amdgcn_mfma_f32_16x16x32_bf16(af[i], bfr[j], acc[i][j], 0,0,0);
    }
    __syncthreads();
  }

  #pragma unroll
  for (int i=0;i<4;i++) {
    #pragma unroll
    for (int reg=0; reg<4; ++reg) {
      int m = m0 + wy*64 + i*16 + g4*4 + reg;
      #pragma unroll
      for (int j=0;j<4;j++) {
        int n = n0 + wx*64 + j*16 + r16;
        float v = acc[i][j][reg];
        float vp = __shfl_xor(v, 1);
        if (!(r16 & 1)) {   // even lane: v = h1, vp = h3
          float hv = v / (1.f + __expf(-v)) * vp;
          hb[((size_t)e*NTOK + m)*F_ + (n>>1)] = f2b(hv);
        }
      }
    }
  }
}

// ---------------------------------------------------------------------------
// Sparse MoE w2 GEMM: scatter-add epilogue out[tok*D+n] += gate*v.
// ---------------------------------------------------------------------------
__global__ __launch_bounds__(256, 2) void moe_w2(
    const us* __restrict__ hb, const us* __restrict__ w2b,
    const int* __restrict__ cnt, const int* __restrict__ tok_idx,
    const float* __restrict__ tok_gate, float* __restrict__ out)
{
  const int e = blockIdx.z;
  const int ce = cnt[e];
  const int m0 = blockIdx.y*128, n0 = blockIdx.x*128;
  if (m0 >= ce) return;
  __shared__ char sm[32768];
  char* smA = sm;
  char* smB = sm + 16384;
  const int tid = threadIdx.x;
  const int wid = tid >> 6, lane = tid & 63;
  const int wy = wid >> 1, wx = wid & 1;
  const int r16 = lane & 15, g4 = lane >> 4;
  const us* Am = hb  + (size_t)e*NTOK*F_;
  const us* Bm = w2b + (size_t)e*D_*F_;

  f32x4 acc[4][4];
  #pragma unroll
  for (int i=0;i<4;i++)
    #pragma unroll
    for(int j=0;j<4;j++) acc[i][j] = (f32x4)0.f;

  for (int kt = 0; kt < 16; ++kt) {
    #pragma unroll
    for (int r = 0; r < 4; ++r) {
      int linear = r*256 + tid;
      int row = linear >> 3, ss = linear & 7;
      int sg = ss ^ (row & 7);
      __builtin_amdgcn_global_load_lds(
        (const __attribute__((address_space(1))) void*)(Am + (size_t)(m0+row)*F_ + kt*64 + sg*8),
        (__attribute__((address_space(3))) void*)(smA + linear*16), 16, 0, 0);
      __builtin_amdgcn_global_load_lds(
        (const __attribute__((address_space(1))) void*)(Bm + (size_t)(n0+row)*F_ + kt*64 + sg*8),
        (__attribute__((address_space(3))) void*)(smB + linear*16), 16, 0, 0);
    }
    __syncthreads();
    #pragma unroll
    for (int kk = 0; kk < 2; ++kk) {
      bf16x8 af[4], bfr[4];
      #pragma unroll
      for (int i=0;i<4;i++){
        int row = wy*64 + i*16 + r16;
        int sl = ((kk<<2) | g4) ^ (row & 7);
        af[i] = *(const bf16x8*)(smA + row*128 + sl*16);
      }
      #pragma unroll
      for (int j=0;j<4;j++){
        int row = wx*64 + j*16 + r16;
        int sl = ((kk<<2) | g4) ^ (row & 7);
        bfr[j] = *(const bf16x8*)(smB + row*128 + sl*16);
      }
      #pragma unroll
      for (int i=0;i<4;i++)
        #pragma unroll
        for (int j=0;j<4;j++)
          acc[i][j] = __builtin_amdgcn_mfma_f32_16x16x32_bf16(af[i], bfr[j], acc[i][j], 0,0,0);
    }
    __syncthreads();
  }

  #pragma unroll
  for (int i=0;i<4;i++) {
    #pragma unroll
    for (int reg=0; reg<4; ++reg) {
      int m = m0 + wy*64 + i*16 + g4*4 + reg;
      if (m < ce) {
        int tok = tok_idx[e*NTOK + m] & (NTOK-1);
        float g = tok_gate[e*NTOK + m];
        #pragma unroll
        for (int j=0;j<4;j++) {
          int n = n0 + wx*64 + j*16 + r16;
          unsafeAtomicAdd(&out[(size_t)tok*D_ + n], g * acc[i][j][reg]);
        }
      }
    }
  }
}

// ---------------------------------------------------------------------------
__global__ void rope_table(const int* __restrict__ pos, float2* __restrict__ cs)
{
  int idx = blockIdx.x*256 + threadIdx.x;   // T*256
  int t = idx >> 8, j = idx & 255;
  float xj = (float)j * (1.0f/256.0f);
  float p32 = (float)pow(10000.0, (double)xj);
  float invf = 1.0f / p32;
  float ang = (float)pos[t] * invf;
  cs[idx] = make_float2(cosf(ang), sinf(ang));
}

// ---------------------------------------------------------------------------
// LN1 -> xn1 fp16 hi/lo planes + roped K planes (interleaved pair order)
// ---------------------------------------------------------------------------
__global__ void ln1_kernel(const float* __restrict__ x, const float* __restrict__ g,
    const float* __restrict__ be, const float2* __restrict__ cs,
    us* __restrict__ xn1h, us* __restrict__ xn1l,
    us* __restrict__ Krh, us* __restrict__ Krl)
{
  const int row = blockIdx.x;           // b*T + t
  const int t = row & (T_-1);
  const int tid = threadIdx.x;
  __shared__ float red[8];
  float v0 = x[(size_t)row*D_ + tid];
  float v1 = x[(size_t)row*D_ + 256 + tid];
  const int wid = tid>>6, lane = tid&63;
  float s = v0 + v1;
  #pragma unroll
  for (int m=1; m<64; m<<=1) s += __shfl_xor(s,m);
  if (lane == 0) red[wid] = s;
  __syncthreads();
  s = red[0]+red[1]+red[2]+red[3];
  float mu = s * (1.f/D_);
  float d0 = v0-mu, d1 = v1-mu;
  float q = d0*d0 + d1*d1;
  #pragma unroll
  for (int m=1; m<64; m<<=1) q += __shfl_xor(q,m);
  __syncthreads();
  if (lane == 0) red[wid] = q;
  __syncthreads();
  q = red[0]+red[1]+red[2]+red[3];
  float var = q * (1.f/D_);
  float rs = rsqrtf(var + 1e-5f);
  float n0 = d0*rs*g[tid]     + be[tid];
  float n1 = d1*rs*g[tid+256] + be[tid+256];
  splitf(n0, xn1h[(size_t)row*D_ + tid],       xn1l[(size_t)row*D_ + tid]);
  splitf(n1, xn1h[(size_t)row*D_ + 256 + tid], xn1l[(size_t)row*D_ + 256 + tid]);
  float2 c = cs[(size_t)t*256 + tid];
  float k0 = n0*c.x - n1*c.y;
  float k1 = n1*c.x + n0*c.y;
  us k0h,k0l,k1h,k1l;
  splitf(k0, k0h, k0l);
  splitf(k1, k1h, k1l);
  size_t kb = (size_t)row*D_ + 2*tid;
  *(unsigned*)(Krh + kb) = (unsigned)k0h | ((unsigned)k1h << 16);
  *(unsigned*)(Krl + kb) = (unsigned)k0l | ((unsigned)k1l << 16);
}

// ---------------------------------------------------------------------------
// Transpose-split both M (with RoPE pair permutation) and V in one launch.
// ---------------------------------------------------------------------------
__global__ void transpose_split2(const float* __restrict__ Mp, const float* __restrict__ Vp,
    us* __restrict__ Mth, us* __restrict__ Mtl,
    us* __restrict__ Vth, us* __restrict__ Vtl)
{
  const int zz = blockIdx.z;
  const float* in = zz ? Vp : Mp;
  us* outh = zz ? Vth : Mth;
  us* outl = zz ? Vtl : Mtl;
  const int R = D_, C = HD;
  __shared__ float tile[32][33];
  const int c0 = blockIdx.x*32, r0 = blockIdx.y*32;
  const int tc = threadIdx.x & 31, tr = threadIdx.x >> 5;  // tr in 0..7
  #pragma unroll
  for (int i=0;i<4;i++)
    tile[tr + 8*i][tc] = in[(size_t)(r0 + tr + 8*i)*C + c0 + tc];
  __syncthreads();
  #pragma unroll
  for (int i=0;i<4;i++) {
    float v = tile[tc][tr + 8*i];
    int j0 = c0 + tr + 8*i;
    int n = j0;
    if (!zz) {
      int jh = j0 & 511;
      n = (j0 & ~511) | ((jh & 255) << 1) | (jh >> 8);
    }
    size_t o = (size_t)n*R + r0 + tc;
    splitf(v, outh[o], outl[o]);
  }
}

// ---------------------------------------------------------------------------
// One-shot MoE weight cast: w1 -> w13b rows 2f, w3 -> rows 2f+1, w2 -> w2b.
// ---------------------------------------------------------------------------
__global__ void cast_moe(const float* __restrict__ w1, const float* __restrict__ w3,
    const float* __restrict__ w2, us* __restrict__ w13b, us* __restrict__ w2b)
{
  const int n1 = E_*F_*D_/4;
  int i = blockIdx.x*256 + threadIdx.x;   // 3*n1 total
  const float* src; int kind;
  int ii = i;
  if (i < n1)            { src = w1; kind = 0; }
  else if (i < 2*n1)     { src = w3; kind = 1; ii = i - n1; }
  else                   { src = w2; kind = 2; ii = i - 2*n1; }
  float4 v = ((const float4*)src)[ii];
  union { us u[4]; uint2 v2; } r;
  r.u[0]=f2b(v.x); r.u[1]=f2b(v.y); r.u[2]=f2b(v.z); r.u[3]=f2b(v.w);
  if (kind == 2) {
    ((uint2*)w2b)[ii] = r.v2;
  } else {
    int e = ii / (F_*D_/4);
    int rem = ii - e*(F_*D_/4);
    int f = rem / (D_/4);
    int d4 = rem - f*(D_/4);
    size_t ob = (size_t)e*(2*F_*D_/4) + (size_t)(2*f+kind)*(D_/4) + d4;
    ((uint2*)w13b)[ob] = r.v2;
  }
}

// ---------------------------------------------------------------------------
// x1 = x + sum_h Opart[h]; out = x1; xn2b = bf16(LN2(x1)); fused router logits
// ---------------------------------------------------------------------------
__global__ void resid_ln2_kernel(const float* __restrict__ x, const us* __restrict__ Opart,
    const float* __restrict__ g, const float* __restrict__ be,
    const float* __restrict__ rw,
    float* __restrict__ out, us* __restrict__ xn2b, float* __restrict__ logits)
{
  const int row = blockIdx.x;
  const int b = row >> 10, t = row & (T_-1);
  const int tid = threadIdx.x;
  __shared__ float red[8];
  __shared__ float red2[4][8];
  float a0 = x[(size_t)row*D_ + tid];
  float a1 = x[(size_t)row*D_ + 256 + tid];
  #pragma unroll
  for (int h=0; h<H_; ++h) {
    const us* op = Opart + ((size_t)(b*8 + h)*T_ + t)*D_;
    H16 u0; u0.u = op[tid];       a0 += (float)u0.h;
    H16 u1; u1.u = op[256 + tid]; a1 += (float)u1.h;
  }
  out[(size_t)row*D_ + tid] = a0;
  out[(size_t)row*D_ + 256 + tid] = a1;
  const int wid = tid>>6, lane = tid&63;
  float s = a0 + a1;
  #pragma unroll
  for (int m=1; m<64; m<<=1) s += __shfl_xor(s,m);
  if (lane == 0) red[wid] = s;
  __syncthreads();
  s = red[0]+red[1]+red[2]+red[3];
  float mu = s * (1.f/D_);
  float d0 = a0-mu, d1 = a1-mu;
  float q = d0*d0 + d1*d1;
  #pragma unroll
  for (int m=1; m<64; m<<=1) q += __shfl_xor(q,m);
  __syncthreads();
  if (lane == 0) red[wid] = q;
  __syncthreads();
  q = red[0]+red[1]+red[2]+red[3];
  float var = q * (1.f/D_);
  float rs = rsqrtf(var + 1e-5f);
  float n0 = d0*rs*g[tid]     + be[tid];
  float n1 = d1*rs*g[tid+256] + be[tid+256];
  xn2b[(size_t)row*D_ + tid]       = f2b(n0);
  xn2b[(size_t)row*D_ + 256 + tid] = f2b(n1);
  float pl[8];
  #pragma unroll
  for (int e=0;e<E_;e++)
    pl[e] = n0*rw[e*D_ + tid] + n1*rw[e*D_ + 256 + tid];
  #pragma unroll
  for (int m=1; m<64; m<<=1)
    #pragma unroll
    for (int e=0;e<E_;e++) pl[e] += __shfl_xor(pl[e], m);
  if (lane == 0)
    #pragma unroll
    for (int e=0;e<E_;e++) red2[wid][e] = pl[e];
  __syncthreads();
  if (tid < 8)
    logits[(size_t)row*8 + tid] = red2[0][tid]+red2[1][tid]+red2[2][tid]+red2[3][tid];
}

// ---------------------------------------------------------------------------
// Router compaction: single block, deterministic slot assignment.
// ---------------------------------------------------------------------------
__global__ __launch_bounds__(1024) void router_compact(
    const float* __restrict__ logits, int* __restrict__ cnt,
    int* __restrict__ tok_idx, float* __restrict__ tok_gate)
{
  const int tid = threadIdx.x;
  __shared__ int sc[1024][8];
  int e1v[4], e2v[4];
  float g1v[4], g2v[4];
  int lc[8] = {0,0,0,0,0,0,0,0};
  #pragma unroll
  for (int i=0;i<4;i++) {
    int tok = tid*4 + i;
    float lg[8];
    float4 a = *(const float4*)(logits + (size_t)tok*8);
    float4 b = *(const float4*)(logits + (size_t)tok*8 + 4);
    lg[0]=a.x; lg[1]=a.y; lg[2]=a.z; lg[3]=a.w;
    lg[4]=b.x; lg[5]=b.y; lg[6]=b.z; lg[7]=b.w;
    int i1 = 0;
    #pragma unroll
    for (int e=1;e<E_;e++) if (lg[e] > lg[i1]) i1 = e;
    int i2 = (i1==0) ? 1 : 0;
    #pragma unroll
    for (int e=0;e<E_;e++) if (e != i1 && lg[e] > lg[i2]) i2 = e;
    float p2 = expf(lg[i2] - lg[i1]);
    float den = 1.f + p2;
    e1v[i] = i1; g1v[i] = 1.f/den;
    e2v[i] = i2; g2v[i] = p2/den;
    lc[i1]++; lc[i2]++;
  }
  #pragma unroll
  for (int e=0;e<E_;e++) sc[tid][e] = lc[e];
  __syncthreads();
  for (int off=1; off<1024; off<<=1) {
    int tmp[8];
    if (tid >= off) {
      #pragma unroll
      for (int e=0;e<E_;e++) tmp[e] = sc[tid-off][e];
    }
    __syncthreads();
    if (tid >= off) {
      #pragma unroll
      for (int e=0;e<E_;e++) sc[tid][e] += tmp[e];
    }
    __syncthreads();
  }
  int run[8];
  #pragma unroll
  for (int e=0;e<E_;e++) run[e] = sc[tid][e] - lc[e];   // exclusive prefix
  if (tid == 0) {
    #pragma unroll
    for (int e=0;e<E_;e++) cnt[e] = sc[1023][e];
  }
  #pragma unroll
  for (int i=0;i<4;i++) {
    int tok = tid*4 + i;
    int s1 = run[e1v[i]]++;
    tok_idx[e1v[i]*NTOK + s1]  = tok;
    tok_gate[e1v[i]*NTOK + s1] = g1v[i];
    int s2 = run[e2v[i]]++;
    tok_idx[e2v[i]*NTOK + s2]  = tok;
    tok_gate[e2v[i]*NTOK + s2] = g2v[i];
  }
}

// ---------------------------------------------------------------------------
extern "C" void kernel_launch(void* const* d_in, const int* in_sizes, int n_in,
                              void* d_out, int out_size, void* d_ws, size_t ws_size,
                              hipStream_t stream)
{
  const float* x    = (const float*)d_in[0];
  const int*   pos  = (const int*)d_in[1];
  const float* ln1g = (const float*)d_in[2];
  const float* ln1b = (const float*)d_in[3];
  const float* M    = (const float*)d_in[4];
  const float* V    = (const float*)d_in[5];
  const float* ln2g = (const float*)d_in[6];
  const float* ln2b = (const float*)d_in[7];
  const float* rw   = (const float*)d_in[8];
  const float* w1   = (const float*)d_in[9];
  const float* w2   = (const float*)d_in[10];
  const float* w3   = (const float*)d_in[11];
  float* out = (float*)d_out;

  char* ws = (char*)d_ws;
  const size_t MB = (size_t)1 << 20;
  const bool merged = ws_size >= (size_t)229*MB;

  // --- persistent across attention phase ---
  float2* cs  = (float2*)(ws + 0);            // 2MB
  us* Krh  = (us*)(ws + 2*MB);                // 4MB (interleaved pair order)
  us* Krl  = (us*)(ws + 6*MB);                // 4MB
  us* valTh   = (us*)(ws + 10*MB);            // 32MB (10..42)
  us* valTl   = (us*)(ws + 42*MB);            // 32MB (42..74)
  us* Qhp     = (us*)(ws + 74*MB);            // 32MB (74..106), dead after S-GEMM
  us* Qlp     = (us*)(ws + 106*MB);           // 32MB (106..138), dead after S-GEMM
  float* S    = (float*)(ws + 138*MB);        // packed: 75.5MB (merged) / 18.9MB/b (fallback)
  // projection-phase temporaries overlay the S region (dead before S written)
  us* xn1h = (us*)(ws + 138*MB);              // 4MB
  us* xn1l = (us*)(ws + 142*MB);              // 4MB
  us* Mth  = (us*)(ws + 146*MB);              // 8MB
  us* Mtl  = (us*)(ws + 154*MB);              // 8MB
  us* Vth  = (us*)(ws + 162*MB);              // 8MB
  us* Vtl  = (us*)(ws + 170*MB);              // 8MB (ends 178)
  // Opart (B*H per-head fp16 partials, 32MB):
  //   merged: over dead Q planes at 74MB; fallback: after fallback S at 157MB.
  us* Opart = merged ? (us*)(ws + 74*MB) : (us*)(ws + 157*MB);
  size_t tail = merged ? 214*MB : 190*MB;
  float* logits = (float*)(ws + tail);                    // 128KB
  us*    xn2b   = (us*)   (ws + tail + 1*MB);             // 4MB
  int*   cnt      = (int*)  (ws + tail + 5*MB);           // 4KB
  int*   tok_idx  = (int*)  (ws + tail + 5*MB + 4096);    // 128KB
  float* tok_gate = (float*)(ws + tail + 5*MB + 4096 + 128*1024); // 128KB
  // MoE temporaries overlay attention-dead regions
  us* w13b = (us*)(ws + 10*MB);               // 16MB (over valT, dead post-PV)
  us* w2b  = (us*)(ws + 26*MB);               // 8MB
  us* hb   = (us*)(ws + 74*MB);               // 64MB (over Q/Opart, dead post-resid)

  rope_table<<<T_, 256, 0, stream>>>(pos, cs);
  ln1_kernel<<<NTOK, 256, 0, stream>>>(x, ln1g, ln1b, cs, xn1h, xn1l, Krh, Krl);
  transpose_split2<<<dim3(HD/32, D_/32, 2), 256, 0, stream>>>(M, V, Mth, Mtl, Vth, Vtl);

  // Q = rope(xn1 @ M) fused epilogue -> Qhp/Qlp (interleaved pair order)
  gemm_ms<4><<<dim3(HD/128, NTOK/128, 1), 256, 0, stream>>>(
      xn1h, xn1l, Mth, Mtl, nullptr, Qhp, Qlp,
      NTOK, HD, D_, D_, D_, HD, cs, 0);
  // valT[h,d,b,t] = V^T @ xn1^T, split store
  gemm_ms<1><<<dim3(NTOK/128, HD/128, 1), 256, 0, stream>>>(
      Vth, Vtl, xn1h, xn1l, nullptr, valTh, valTl,
      HD, NTOK, D_, D_, D_, NTOK, nullptr, 0);

  // --- attention: packed causal S -> softmax -> PV ---
  // z-major grids: xcd = z%8 = head; heavy row-tiles dispatched first.
  if (merged) {
    gemm_ms<2><<<dim3(B_*H_, 8, 8), 256, 0, stream>>>(
        Qhp, Qlp, Krh, Krl, S, nullptr, nullptr,
        T_, T_, D_, HD, D_, 128, nullptr, 0);
    softmax_pk<<<B_*H_*T_, 256, 0, stream>>>(S);
    gemm_ms<5><<<dim3(B_*H_, 8, 4), 256, 0, stream>>>(
        (const us*)S, nullptr, valTh, valTl, nullptr, Opart, nullptr,
        T_, D_, T_, 0, NTOK, D_, nullptr, 0);
  } else {
    for (int b = 0; b < B_; ++b) {
      gemm_ms<2><<<dim3(H_, 8, 8), 256, 0, stream>>>(
          Qhp, Qlp, Krh, Krl, S, nullptr, nullptr,
          T_, T_, D_, HD, D_, 128, nullptr, b);
      softmax_pk<<<H_*T_, 256, 0, stream>>>(S);
      gemm_ms<5><<<dim3(H_, 8, 4), 256, 0, stream>>>(
          (const us*)S, nullptr, valTh, valTl, nullptr, Opart, nullptr,
          T_, D_, T_, 0, NTOK, D_, nullptr, b);
    }
  }

  resid_ln2_kernel<<<NTOK, 256, 0, stream>>>(x, Opart, ln2g, ln2b, rw, out, xn2b, logits);
  router_compact<<<1, 1024, 0, stream>>>(logits, cnt, tok_idx, tok_gate);

  cast_moe<<<3*(E_*F_*D_/4)/256, 256, 0, stream>>>(w1, w3, w2, w13b, w2b);

  moe_w13<<<dim3(2*F_/128, NTOK/128, E_), 256, 0, stream>>>(
      xn2b, w13b, cnt, tok_idx, hb);
  moe_w2<<<dim3(D_/128, NTOK/128, E_), 256, 0, stream>>>(
      hb, w2b, cnt, tok_idx, tok_gate, out);
}